// Round 1
// 398.401 us; speedup vs baseline: 1.0525x; 1.0525x over previous
//
#include <hip/hip_runtime.h>
#include <stdint.h>

#define B_ 16
#define C_ 512
#define N_ 4096

typedef float f32x4 __attribute__((ext_vector_type(4)));
typedef __bf16 bf16x8 __attribute__((ext_vector_type(8)));

// fp32 -> bf16 round-to-nearest-even (inputs are finite normals; no NaN path needed)
static __device__ __forceinline__ unsigned short f2bf(float f) {
    unsigned int u = __float_as_uint(f);
    u += 0x7fffu + ((u >> 16) & 1u);
    return (unsigned short)(u >> 16);
}

// async global->LDS, 16B per lane (global_load_lds_dwordx4)
static __device__ __forceinline__ void gload_lds16(const void* g, void* l) {
    __builtin_amdgcn_global_load_lds(
        (__attribute__((address_space(1))) unsigned int*)(g),
        (__attribute__((address_space(3))) unsigned int*)(l),
        16, 0, 0);
}

// Cooperative stage of one 128x32 A-tile and 128x32 B-tile into LDS.
// 4 global_load_lds_dwordx4 per thread per call => vmcnt +4 per wave.
static __device__ __forceinline__ void stage_pair(const char* Ab, const char* Bb,
                                                  char* as, char* bs, int tid,
                                                  int rowBytes, int m0, int n0, int kByte) {
#pragma unroll
    for (int i = 0; i < 2; ++i) {
        int o = (i * 256 + tid) * 16;            // LDS byte offset, 0..8191
        int mrow = o >> 6, inrow = o & 63;       // 64 B per 32-elem bf16 row
        gload_lds16(Ab + (size_t)(m0 + mrow) * rowBytes + kByte + inrow, as + o);
        gload_lds16(Bb + (size_t)(n0 + mrow) * rowBytes + kByte + inrow, bs + o);
    }
}

// ---------------------------------------------------------------------------
// Kernel 1: x (fp32, BxCxN) -> q16 (bf16, BxCxN) and qt16 (bf16, BxNxC)
// Register 4x4 micro-tile transpose: no LDS, no barriers.
//   lane layout: t&15 -> n-subgroup (keeps x loads 256B-coalesced,
//                q stores 128B-coalesced), t>>4 -> c-subgroup.
// ---------------------------------------------------------------------------
__global__ __launch_bounds__(256)
void convert_transpose(const float* __restrict__ x,
                       unsigned short* __restrict__ q16,
                       unsigned short* __restrict__ qt16) {
    int b = blockIdx.z;
    int t = threadIdx.x;
    int c0 = blockIdx.y * 64 + (t >> 4) * 4;
    int n0 = blockIdx.x * 64 + (t & 15) * 4;

    const float* xb = x + ((size_t)b * C_ + c0) * N_ + n0;
    unsigned short h[4][4];
#pragma unroll
    for (int i = 0; i < 4; ++i) {
        float4 v = *(const float4*)(xb + (size_t)i * N_);
        h[i][0] = f2bf(v.x); h[i][1] = f2bf(v.y);
        h[i][2] = f2bf(v.z); h[i][3] = f2bf(v.w);
    }
    unsigned short* qb = q16 + ((size_t)b * C_ + c0) * N_ + n0;
#pragma unroll
    for (int i = 0; i < 4; ++i) {
        ushort4 p; p.x = h[i][0]; p.y = h[i][1]; p.z = h[i][2]; p.w = h[i][3];
        *(ushort4*)(qb + (size_t)i * N_) = p;
    }
    unsigned short* qtb = qt16 + ((size_t)b * N_ + n0) * C_ + c0;
#pragma unroll
    for (int j = 0; j < 4; ++j) {
        ushort4 p; p.x = h[0][j]; p.y = h[1][j]; p.z = h[2][j]; p.w = h[3][j];
        *(ushort4*)(qtb + (size_t)j * C_) = p;
    }
}

// ---------------------------------------------------------------------------
// Kernel 2: energy[b] = Q[b] . Q[b]^T   (M=N=512, K=4096, bf16 MFMA)
// Depth-2 counted-vmcnt pipeline (T3+T4): 3 LDS buffers, stage tile t+2 each
// iter, wait vmcnt(4) (never 0 in steady state), single raw barrier per iter.
// Split-K x2 across blockIdx.z parity -> 512 blocks = 2 blocks/CU.
// ---------------------------------------------------------------------------
template<int KROW, int NT>
__global__ __launch_bounds__(256)
void gemm_bt_energy(const unsigned short* __restrict__ q16,
                    float* __restrict__ e0, float* __restrict__ e1) {
    int zb = blockIdx.z;
    int b = zb >> 1, ks = zb & 1;
    int kbeg = ks * (NT * 32);
    const char* Ab = (const char*)(q16 + (size_t)b * C_ * KROW);
    int m0 = blockIdx.y * 128, n0 = blockIdx.x * 128;

    __shared__ unsigned short As[3][128 * 32];
    __shared__ unsigned short Bs[3][128 * 32];

    int t = threadIdx.x;
    int lane = t & 63, wave = t >> 6;
    int wm = (wave >> 1) * 64, wn = (wave & 1) * 64;
    int qd = lane >> 4, r = lane & 15;

    f32x4 acc[4][4] = {};

    const int rowB = KROW * 2;
    stage_pair(Ab, Ab, (char*)As[0], (char*)Bs[0], t, rowB, m0, n0, kbeg * 2);
    stage_pair(Ab, Ab, (char*)As[1], (char*)Bs[1], t, rowB, m0, n0, (kbeg + 32) * 2);

    int bufi = 0;
    for (int tt = 0; tt < NT; ++tt) {
        // tile tt ready (oldest 4 loads landed); lgkm(0) guarantees this
        // wave's previous-iter ds_reads are complete before the barrier,
        // so staging may overwrite that buffer after the barrier.
        if (tt < NT - 1) asm volatile("s_waitcnt vmcnt(4) lgkmcnt(0)" ::: "memory");
        else             asm volatile("s_waitcnt vmcnt(0) lgkmcnt(0)" ::: "memory");
        __builtin_amdgcn_s_barrier();

        if (tt + 2 < NT) {
            int nb = bufi + 2; if (nb >= 3) nb -= 3;
            stage_pair(Ab, Ab, (char*)As[nb], (char*)Bs[nb], t, rowB,
                       m0, n0, (kbeg + (tt + 2) * 32) * 2);
        }

        const unsigned short* as = As[bufi];
        const unsigned short* bs = Bs[bufi];
        bf16x8 af[4], bfr[4];
#pragma unroll
        for (int i = 0; i < 4; ++i)
            af[i] = *(const bf16x8*)&as[(wm + i * 16 + r) * 32 + qd * 8];
#pragma unroll
        for (int j = 0; j < 4; ++j)
            bfr[j] = *(const bf16x8*)&bs[(wn + j * 16 + r) * 32 + qd * 8];

        __builtin_amdgcn_s_setprio(1);
#pragma unroll
        for (int i = 0; i < 4; ++i)
#pragma unroll
            for (int j = 0; j < 4; ++j)
                acc[i][j] = __builtin_amdgcn_mfma_f32_16x16x32_bf16(af[i], bfr[j], acc[i][j], 0, 0, 0);
        __builtin_amdgcn_s_setprio(0);

        if (++bufi == 3) bufi = 0;
    }

    float* Db = (ks ? e1 : e0) + (size_t)b * C_ * C_;
#pragma unroll
    for (int i = 0; i < 4; ++i)
#pragma unroll
        for (int j = 0; j < 4; ++j) {
            int row = m0 + wm + i * 16 + qd * 4;
            int col = n0 + wn + j * 16 + r;
#pragma unroll
            for (int rr = 0; rr < 4; ++rr)
                Db[(size_t)(row + rr) * C_ + col] = acc[i][j][rr];
        }
}

// ---------------------------------------------------------------------------
// Kernel 3: attention = softmax(max - energy) = softmax(-energy), row-wise,
// summing the two split-K partials. One block per (b,c) row; output bf16.
// ---------------------------------------------------------------------------
__global__ __launch_bounds__(256)
void softmax_neg(const float* __restrict__ e0, const float* __restrict__ e1,
                 unsigned short* __restrict__ att) {
    size_t row = blockIdx.x;
    const float* a = e0 + row * C_;
    const float* c = e1 + row * C_;
    int t = threadIdx.x;

    float x0 = a[t] + c[t], x1 = a[t + 256] + c[t + 256];
    float m = fminf(x0, x1);                 // min(e) == -max(-e)
#pragma unroll
    for (int off = 32; off > 0; off >>= 1) m = fminf(m, __shfl_down(m, off, 64));
    __shared__ float red[8];
    if ((t & 63) == 0) red[t >> 6] = m;
    __syncthreads();
    m = fminf(fminf(red[0], red[1]), fminf(red[2], red[3]));

    float p0 = __expf(m - x0), p1 = __expf(m - x1);   // exp(-e - max(-e)) in [0,1]
    float s = p0 + p1;
#pragma unroll
    for (int off = 32; off > 0; off >>= 1) s += __shfl_down(s, off, 64);
    if ((t & 63) == 0) red[4 + (t >> 6)] = s;
    __syncthreads();
    s = red[4] + red[5] + red[6] + red[7];
    float inv = 1.0f / s;

    att[row * C_ + t]       = f2bf(p0 * inv);
    att[row * C_ + t + 256] = f2bf(p1 * inv);
}

// ---------------------------------------------------------------------------
// Kernel 4: y[b] = gamma * (attention[b] . Q[b]) + x[b]
// A = att (512x512 bf16), B = Qt (4096x512 bf16), K=512.
// Same depth-2 counted-vmcnt pipeline; fused epilogue reads x, writes y.
// ---------------------------------------------------------------------------
__global__ __launch_bounds__(256)
void gemm_bt_out(const unsigned short* __restrict__ att,
                 const unsigned short* __restrict__ qt16,
                 const float* __restrict__ x,
                 const float* __restrict__ gamma,
                 float* __restrict__ y) {
    const int K = 512;
    const int NT = K / 32;   // 16
    int b = blockIdx.z;
    const char* Ab = (const char*)(att  + (size_t)b * C_ * K);
    const char* Bb = (const char*)(qt16 + (size_t)b * N_ * K);
    int m0 = blockIdx.y * 128;    // c
    int n0 = blockIdx.x * 128;    // n (spatial)

    __shared__ unsigned short As[3][128 * 32];
    __shared__ unsigned short Bs[3][128 * 32];

    int t = threadIdx.x;
    int lane = t & 63, wave = t >> 6;
    int wm = (wave >> 1) * 64, wn = (wave & 1) * 64;
    int qd = lane >> 4, r = lane & 15;

    f32x4 acc[4][4] = {};

    const int rowB = K * 2;
    stage_pair(Ab, Bb, (char*)As[0], (char*)Bs[0], t, rowB, m0, n0, 0);
    stage_pair(Ab, Bb, (char*)As[1], (char*)Bs[1], t, rowB, m0, n0, 64);

    int bufi = 0;
    for (int tt = 0; tt < NT; ++tt) {
        if (tt < NT - 1) asm volatile("s_waitcnt vmcnt(4) lgkmcnt(0)" ::: "memory");
        else             asm volatile("s_waitcnt vmcnt(0) lgkmcnt(0)" ::: "memory");
        __builtin_amdgcn_s_barrier();

        if (tt + 2 < NT) {
            int nb = bufi + 2; if (nb >= 3) nb -= 3;
            stage_pair(Ab, Bb, (char*)As[nb], (char*)Bs[nb], t, rowB,
                       m0, n0, (tt + 2) * 64);
        }

        const unsigned short* as = As[bufi];
        const unsigned short* bs = Bs[bufi];
        bf16x8 af[4], bfr[4];
#pragma unroll
        for (int i = 0; i < 4; ++i)
            af[i] = *(const bf16x8*)&as[(wm + i * 16 + r) * 32 + qd * 8];
#pragma unroll
        for (int j = 0; j < 4; ++j)
            bfr[j] = *(const bf16x8*)&bs[(wn + j * 16 + r) * 32 + qd * 8];

        __builtin_amdgcn_s_setprio(1);
#pragma unroll
        for (int i = 0; i < 4; ++i)
#pragma unroll
            for (int j = 0; j < 4; ++j)
                acc[i][j] = __builtin_amdgcn_mfma_f32_16x16x32_bf16(af[i], bfr[j], acc[i][j], 0, 0, 0);
        __builtin_amdgcn_s_setprio(0);

        if (++bufi == 3) bufi = 0;
    }

    float g = gamma[0];
    const float* xb = x + (size_t)b * C_ * N_;
    float*       yb = y + (size_t)b * C_ * N_;
#pragma unroll
    for (int i = 0; i < 4; ++i)
#pragma unroll
        for (int j = 0; j < 4; ++j) {
            int row = m0 + wm + i * 16 + qd * 4;
            int col = n0 + wn + j * 16 + r;
#pragma unroll
            for (int rr = 0; rr < 4; ++rr) {
                size_t idx = (size_t)(row + rr) * N_ + col;
                yb[idx] = g * acc[i][j][rr] + xb[idx];
            }
        }
}

// ---------------------------------------------------------------------------
// Workspace layout (bytes):
//   q16    @ 0          : 16*512*4096*2 = 67,108,864
//   qt16   @ 67108864   : 67,108,864
//   att16  @ 134217728  :  8,388,608
//   energy0@ 142606336  : 16,777,216      -> total 159,383,552
//   energy1 = d_out (scratch; fully overwritten by gemm_bt_out afterwards)
// ---------------------------------------------------------------------------
extern "C" void kernel_launch(void* const* d_in, const int* in_sizes, int n_in,
                              void* d_out, int out_size, void* d_ws, size_t ws_size,
                              hipStream_t stream) {
    const float* x     = (const float*)d_in[0];
    const float* gamma = (const float*)d_in[1];
    float*       y     = (float*)d_out;

    char* ws = (char*)d_ws;
    unsigned short* q16    = (unsigned short*)(ws);
    unsigned short* qt16   = (unsigned short*)(ws + 67108864);
    unsigned short* att16  = (unsigned short*)(ws + 134217728);
    float*          energy0= (float*)(ws + 142606336);
    float*          energy1= (float*)d_out;   // scratch until gemm_bt_out runs

    convert_transpose<<<dim3(N_ / 64, C_ / 64, B_), dim3(256), 0, stream>>>(x, q16, qt16);
    gemm_bt_energy<N_, N_ / 64><<<dim3(C_ / 128, C_ / 128, B_ * 2), dim3(256), 0, stream>>>(q16, energy0, energy1);
    softmax_neg<<<dim3(B_ * C_), dim3(256), 0, stream>>>(energy0, energy1, att16);
    gemm_bt_out<<<dim3(N_ / 128, C_ / 128, B_), dim3(256), 0, stream>>>(att16, qt16, x, gamma, y);
}